// Round 13
// baseline (477.446 us; speedup 1.0000x reference)
//
#include <hip/hip_runtime.h>
#include <hip/hip_bf16.h>

#define D 256
#define TE 64          // messages per tile (full 256 cols per block)
#define BK 64          // K-chunk
#define NCHUNK 12      // 4 groups x [E | E*H | H]
#define LEAKY 0.01f
#define EPS 1e-5f

typedef float f32x4 __attribute__((ext_vector_type(4)));
typedef short s16x8 __attribute__((ext_vector_type(8)));

__device__ __forceinline__ unsigned short f2bf(float f){
  union { float f; unsigned int u; } v; v.f = f;
  unsigned int u = v.u;
  return (unsigned short)((u + 0x7fffu + ((u >> 16) & 1u)) >> 16);
}
// HW pack: D.lo = bf16(lo), D.hi = bf16(hi), RNE — 1 VALU op.
__device__ __forceinline__ unsigned int cvtpk(float lo, float hi){
  unsigned int r;
  asm("v_cvt_pk_bf16_f32 %0, %1, %2" : "=v"(r) : "v"(lo), "v"(hi));
  return r;
}

// Fragment-major bf16 image of folded weights, per dir (no col-half split).
// tile t = dir*12 + c (32 KB each); within: [ks][j][lane][e]
// col = j*16 + (lane&15), j=0..15; k_local = ks*32 + (lane>>4)*8 + e; x = g*64+k_local.
// A wave's B-fragment load is 64 lanes x 16B CONTIGUOUS (1 KB).
__global__ void prep_w(const float* __restrict__ Wf, const float* __restrict__ Wb,
                       unsigned short* __restrict__ Wimg)
{
  int i = blockIdx.x * 256 + threadIdx.x;       // 2*12*16384 = 393216
  int inner = i & 16383;
  int t = i >> 14;                              // dir*12 + c
  int c = t % 12;
  int dir = t / 12;
  int g = c / 3, part = c - g * 3;
  int e    = inner & 7;
  int lane = (inner >> 3) & 63;
  int j    = (inner >> 9) & 15;
  int ks   = inner >> 13;
  int kloc = ks * 32 + (lane >> 4) * 8 + e;
  int x = g * 64 + kloc;                        // original feature index
  int col = j * 16 + (lane & 15);
  const float* row = (dir ? Wb : Wf) + (long)col * (4 * D);
  // raw = [Hh | E | Hh+E | Hh*E]:
  float v;
  if (part == 0)      v = row[256 + x] + row[512 + x];   // E coeff
  else if (part == 1) v = row[768 + x];                  // Hh*E coeff
  else                v = row[x] + row[512 + x];         // Hh coeff
  Wimg[(size_t)t * 16384 + inner] = f2bf(v);
}

// Per-dir dst histogram: cnt[0..n) = fwd (dst=tail), cnt[n..2n) = back (dst=head)
__global__ void count2(const int* __restrict__ ht, int* __restrict__ cnt,
                       int n_edges, int n_nodes)
{
  int e = blockIdx.x * 256 + threadIdx.x;
  if (e < n_edges){
    atomicAdd(&cnt[ht[2*e+1]], 1);
    atomicAdd(&cnt[n_nodes + ht[2*e]], 1);
  }
}

__global__ void scan_sums(const int* __restrict__ cnt, int* __restrict__ bsum, int N2)
{
  int t = threadIdx.x, b = blockIdx.x;
  int i = b * 1024 + t;
  int v = (i < N2) ? cnt[i] : 0;
  #pragma unroll
  for (int o = 32; o > 0; o >>= 1) v += __shfl_down(v, o);
  __shared__ int red[16];
  int lane = t & 63, wv = t >> 6;
  if (lane == 0) red[wv] = v;
  __syncthreads();
  if (t == 0){ int s = 0; for (int k = 0; k < 16; ++k) s += red[k]; bsum[b] = s; }
}

__global__ void scan_bases(const int* __restrict__ bsum, int* __restrict__ bases, int nb)
{
  if (threadIdx.x == 0 && blockIdx.x == 0){
    int a = 0;
    for (int k = 0; k < nb; ++k){ bases[k] = a; a += bsum[k]; }
  }
}

__global__ void scan_off(const int* __restrict__ cnt, const int* __restrict__ bases,
                         int* __restrict__ off, int N2)
{
  int t = threadIdx.x, b = blockIdx.x;
  int i = b * 1024 + t;
  int v = (i < N2) ? cnt[i] : 0;
  int lane = t & 63, wv = t >> 6;
  int x = v;
  #pragma unroll
  for (int o = 1; o < 64; o <<= 1){ int y = __shfl_up(x, o); if (lane >= o) x += y; }
  __shared__ int ws[16];
  if (lane == 63) ws[wv] = x;
  __syncthreads();
  if (t == 0){ int a = 0; for (int k = 0; k < 16; ++k){ int tmp = ws[k]; ws[k] = a; a += tmp; } }
  __syncthreads();
  if (i < N2) off[i] = bases[b] + ws[wv] + x - v;
}

// Build dst-sorted lists: positions [0,NE) = fwd sorted by tail, [NE,2NE) = back by head.
__global__ void scatter_msgs(const int* __restrict__ ht, const int* __restrict__ off,
                             int* __restrict__ cursor, int* __restrict__ perm,
                             int* __restrict__ dstS, int* __restrict__ hS,
                             int n_edges, int n_nodes)
{
  int m = blockIdx.x * 256 + threadIdx.x;
  if (m >= 2 * n_edges) return;
  int e  = (m < n_edges) ? m : m - n_edges;
  int hd = ht[2*e], tl = ht[2*e+1];
  int dst = (m < n_edges) ? tl : hd;
  int oth = (m < n_edges) ? hd : tl;
  int idx = ((m < n_edges) ? 0 : n_nodes) + dst;
  int pos = off[idx] + atomicAdd(&cursor[idx], 1);
  perm[pos] = e; dstS[pos] = dst; hS[pos] = oth;
}

// 64 edges x 256 cols per block: A staged ONCE per (tile,dir) — half the
// gather/pack/LDS work per output vs the 128x128 h-split. 8 waves of 32x64;
// B frags in registers (dbuf, coalesced 1KB loads); R12 pipeline otherwise.
__global__ __launch_bounds__(512, 4) void edge_gemm(
    const float* __restrict__ H, const float* __restrict__ E,
    const int* __restrict__ perm, const int* __restrict__ dstS,
    const int* __restrict__ hS, const unsigned short* __restrict__ Wimg,
    float* __restrict__ agg, int n_edges, int n_nodes)
{
  __shared__ char smem[65536];     // loop: A dbuf in first 16K; epilogue: Cs 64K
  __shared__ int sDst[TE];
  char (*sAl)[8192] = (char(*)[8192])smem;

  // Bijective XCD-chunked swizzle (keeps dir-lists chunked per XCD).
  const int nwg  = gridDim.x;
  const int orig = blockIdx.x;
  const int xcd  = orig & 7;
  const int lq = nwg >> 3, lr = nwg & 7;
  const int L = (xcd < lr ? xcd * (lq + 1) : lr * (lq + 1) + (xcd - lr) * lq)
                + (orig >> 3);
  const int tile = L >> 1;
  const int dir  = L & 1;
  const int pos0 = tile * TE;      // within dir-list

  const int tid  = threadIdx.x;
  const int lane = tid & 63;
  const int wave = tid >> 6;      // 0..7

  // A staging: thread -> 2 rows x 4 cols. cg = col group, rows rg*2+i.
  const int cg = tid & 15;
  const int rg = tid >> 4;        // 0..31
  const float* eptr[2]; const float* hptr[2];
  #pragma unroll
  for (int i = 0; i < 2; ++i){
    int row = rg * 2 + i;
    int rp  = pos0 + row;
    bool pad = (rp >= n_edges);
    int gpos = dir * n_edges + (pad ? (n_edges - 1) : rp);
    eptr[i] = E + (long)perm[gpos] * D;
    hptr[i] = H + (long)hS[gpos] * D;
    if (cg == 0) sDst[row] = pad ? 0x7fffffff : dstS[gpos];
  }
  __syncthreads();

  const char* wqB = (const char*)Wimg + (size_t)dir * NCHUNK * 32768 + lane * 16;

  f32x4 acc[2][4];
  #pragma unroll
  for (int mi = 0; mi < 2; ++mi)
    #pragma unroll
    for (int ni = 0; ni < 4; ++ni)
      acc[mi][ni] = (f32x4){0.f, 0.f, 0.f, 0.f};

  float4 sl0[2], sl1[2];          // A reg slots: A(x) -> slot (x&1)
  float4 Ev[2];                   // persistent E regs across a part-triplet
  s16x8 bA[8], bB[8];             // B frag dbuf: chunk c uses (c&1)?bB:bA

  const int rlo = lane & 15;
  const int khi = lane >> 4;
  const int wm = wave >> 2;       // 0..1: 32-row slab
  const int wn = wave & 3;        // 0..3: 64-col slab

  #define ISSUE_A(c) {                                                       \
    const int g_ = (c) / 3, part_ = (c) % 3;                                 \
    float4* dst_ = ((c) & 1) ? sl1 : sl0;                                    \
    _Pragma("unroll")                                                        \
    for (int i = 0; i < 2; ++i)                                              \
      dst_[i] = *(const float4*)((part_ == 0 ? eptr[i] : hptr[i])            \
                                 + g_ * 64 + cg * 4);                        \
  }

  #define WRITE_A(c, buf) {                                                  \
    const int part_ = (c) % 3;                                               \
    float4* src_ = ((c) & 1) ? sl1 : sl0;                                    \
    _Pragma("unroll")                                                        \
    for (int i = 0; i < 2; ++i){                                             \
      int row = rg * 2 + i;                                                  \
      float4 v;                                                              \
      if (part_ == 0){ Ev[i] = src_[i]; v = src_[i]; }                       \
      else if (part_ == 1) v = make_float4(Ev[i].x*src_[i].x,                \
          Ev[i].y*src_[i].y, Ev[i].z*src_[i].z, Ev[i].w*src_[i].w);          \
      else v = src_[i];                                                      \
      uint2 w; w.x = cvtpk(v.x, v.y); w.y = cvtpk(v.z, v.w);                 \
      int off = (row * 128 + cg * 8) ^ ((row & 7) << 4);                     \
      *(uint2*)(&sAl[buf][off]) = w;                                         \
    }                                                                        \
  }

  // 8 coalesced 16B loads: B frags (ks 0/1) x (ni 0..3) for this wave's 64 cols.
  #define LOAD_B(c, dst_) {                                                  \
    const char* bb = wqB + (size_t)(c) * 32768;                              \
    _Pragma("unroll")                                                        \
    for (int ni = 0; ni < 4; ++ni){                                          \
      dst_[ni]     = *(const s16x8*)(bb + (wn * 4 + ni) * 1024);             \
      dst_[4 + ni] = *(const s16x8*)(bb + 16384 + (wn * 4 + ni) * 1024);     \
    }                                                                        \
  }

  // ---- Prologue ----
  ISSUE_A(0);
  ISSUE_A(1);
  LOAD_B(0, bA);
  WRITE_A(0, 0);
  ISSUE_A(2);
  __syncthreads();

  // ---- Main loop (R7/R12-proven pipeline) ----
  #pragma unroll
  for (int c = 0; c < NCHUNK; ++c){
    const int cur = c & 1;
    if (c + 1 < NCHUNK){
      if (cur) { LOAD_B(c + 1, bA); } else { LOAD_B(c + 1, bB); }
      WRITE_A(c + 1, cur ^ 1);
    }
    if (c + 3 < NCHUNK){
      ISSUE_A(c + 3);
    }
    #pragma unroll
    for (int ks = 0; ks < 2; ++ks){
      const int kb = (ks * 32 + khi * 8) * 2;
      s16x8 af[2];
      #pragma unroll
      for (int mi = 0; mi < 2; ++mi){
        int row = wm * 32 + mi * 16 + rlo;
        af[mi] = *(const s16x8*)(&sAl[cur][(row * 128 + kb) ^ ((row & 7) << 4)]);
      }
      #pragma unroll
      for (int mi = 0; mi < 2; ++mi)
        #pragma unroll
        for (int ni = 0; ni < 4; ++ni)
          acc[mi][ni] = __builtin_amdgcn_mfma_f32_16x16x32_bf16(
              af[mi], cur ? bB[ks * 4 + ni] : bA[ks * 4 + ni],
              acc[mi][ni], 0, 0, 0);
    }
    if (c + 1 < NCHUNK) __syncthreads();
  }
  #undef ISSUE_A
  #undef WRITE_A
  #undef LOAD_B

  // ---- Epilogue: C -> LDS, segmented run-reduce over dst-sorted rows ----
  __syncthreads();                 // all MFMA LDS reads done; smem reusable
  float* Cs = (float*)smem;        // [64][256], bank-rotated by row
  #pragma unroll
  for (int mi = 0; mi < 2; ++mi)
    #pragma unroll
    for (int ni = 0; ni < 4; ++ni)
      #pragma unroll
      for (int r = 0; r < 4; ++r){
        int row = wm * 32 + mi * 16 + khi * 4 + r;
        int col = wn * 64 + ni * 16 + rlo;
        int cw = (col + ((row & 7) << 2)) & 255;
        Cs[row * 256 + cw] = acc[mi][ni][r];
      }
  __syncthreads();

  {
    const int col = tid & 255;
    const int q   = tid >> 8;          // 2 row-halves of 32
    int r0 = q << 5;
    if (q > 0 && sDst[r0] == sDst[r0 - 1]){
      int pd = sDst[r0 - 1];
      int rcap = (q << 5) + 32;
      while (r0 < rcap && sDst[r0] == pd) r0++;
    }
    const int rend = (q << 5) + 32;
    for (int r = r0; r < rend; ){
      int d = sDst[r];
      float s = 0.f;
      int rr = r;
      while (rr < TE && sDst[rr] == d){
        s += Cs[rr * 256 + ((col + ((rr & 7) << 2)) & 255)];
        rr++;
      }
      if (d < n_nodes)
        atomicAdd(agg + (long)d * D + col, s);
      r = rr;
    }
  }
}

__global__ __launch_bounds__(256) void finish(
    const float* __restrict__ agg, const int* __restrict__ cnt_i,
    const float* __restrict__ H, const float* __restrict__ bias_f,
    const float* __restrict__ bias_b, const float* __restrict__ gamma,
    const float* __restrict__ beta, float* __restrict__ out, int n_nodes)
{
  const int n = blockIdx.x;
  const int j = threadIdx.x;
  int cf = cnt_i[n], cb = cnt_i[n_nodes + n];
  float c = (float)(cf + cb); c = c < 1.f ? 1.f : c;
  float a = (agg[(long)n * D + j] + (float)cf * bias_f[j] + (float)cb * bias_b[j]) / c;
  float x = (a > 0.f ? a : LEAKY * a) + H[(long)n * D + j];
  float s1 = x, s2 = x * x;
  #pragma unroll
  for (int off = 32; off > 0; off >>= 1){
    s1 += __shfl_xor(s1, off);
    s2 += __shfl_xor(s2, off);
  }
  __shared__ float rs[8];
  if ((j & 63) == 0){ rs[j >> 6] = s1; rs[4 + (j >> 6)] = s2; }
  __syncthreads();
  float t1 = rs[0] + rs[1] + rs[2] + rs[3];
  float t2 = rs[4] + rs[5] + rs[6] + rs[7];
  float mu = t1 * (1.f / D);
  float var = t2 * (1.f / D) - mu * mu;
  float r = rsqrtf(var + EPS);
  out[(long)n * D + j] = (x - mu) * r * gamma[j] + beta[j];
}

extern "C" void kernel_launch(void* const* d_in, const int* in_sizes, int n_in,
                              void* d_out, int out_size, void* d_ws, size_t ws_size,
                              hipStream_t stream)
{
  const float* H      = (const float*)d_in[0];
  const float* E      = (const float*)d_in[1];
  const int*   ht     = (const int*)d_in[2];
  const float* W_fwd  = (const float*)d_in[3];
  const float* b_fwd  = (const float*)d_in[4];
  const float* W_back = (const float*)d_in[5];
  const float* b_back = (const float*)d_in[6];
  const float* gamma  = (const float*)d_in[7];
  const float* beta   = (const float*)d_in[8];
  float* out = (float*)d_out;

  const int n_nodes = in_sizes[0] / D;
  const int n_edges = in_sizes[2] / 2;
  const int N2 = 2 * n_nodes;
  const int NM = 2 * n_edges;

  char* p = (char*)d_ws;
  float* agg    = (float*)p;  p += (size_t)n_nodes * D * 4;
  int*   cnt_i  = (int*)p;    p += (size_t)N2 * 4;
  int*   cursor = (int*)p;    p += (size_t)N2 * 4;
  size_t zbytes = (size_t)(p - (char*)d_ws);          // agg + cnt + cursor
  int*   off    = (int*)p;    p += (size_t)N2 * 4;
  int*   bsum   = (int*)p;    p += 128 * 4;
  int*   bases  = (int*)p;    p += 128 * 4;
  int*   perm   = (int*)p;    p += (size_t)NM * 4;
  int*   dstS   = (int*)p;    p += (size_t)NM * 4;
  int*   hS     = (int*)p;    p += (size_t)NM * 4;
  unsigned short* Wimg = (unsigned short*)p;

  const int nscan = (N2 + 1023) / 1024;

  hipMemsetAsync(d_ws, 0, zbytes, stream);
  prep_w<<<(2 * NCHUNK * 16384) / 256, 256, 0, stream>>>(W_fwd, W_back, Wimg);
  count2<<<(n_edges + 255) / 256, 256, 0, stream>>>(ht, cnt_i, n_edges, n_nodes);
  scan_sums<<<nscan, 1024, 0, stream>>>(cnt_i, bsum, N2);
  scan_bases<<<1, 64, 0, stream>>>(bsum, bases, nscan);
  scan_off<<<nscan, 1024, 0, stream>>>(cnt_i, bases, off, N2);
  scatter_msgs<<<(NM + 255) / 256, 256, 0, stream>>>(ht, off, cursor, perm, dstS, hS,
                                                     n_edges, n_nodes);
  const int ntiles = (n_edges + TE - 1) / TE;
  edge_gemm<<<ntiles * 2, 512, 0, stream>>>(H, E, perm, dstS, hS, Wimg, agg,
                                            n_edges, n_nodes);
  finish<<<n_nodes, 256, 0, stream>>>(agg, cnt_i, H, b_fwd, b_back, gamma, beta,
                                      out, n_nodes);
}